// Round 13
// baseline (18306.346 us; speedup 1.0000x reference)
//
#include <hip/hip_runtime.h>
#include <math.h>

// DomainTransformFilter on [8,3,1024,1024] f32.
// Reference: 3 iterations of {61-tap H Gaussian, 61-tap V Gaussian},
// replicate pad, sigma=10/20/40. Edge-weight multiplies s=w/(w+1e-8) are
// within 7.4e-8 of 1 and dropped (validated: absmax 3.9e-3, thr ~1.1e-2).
//
// Round-13. Fusion structure (measured r12: passed, absmax 3.9e-3, FETCH
// exactly ideal, 0 bank conflicts) + fixed inner loop. r12's hfused burned
// 123 us of VALU-issue vs a 51 us FMA floor (2.4x bloat) at 37.8% busy:
// the 181 kernarg weights forced in-loop s_load refetches, and SMEM+DS
// share lgkmcnt OUT-OF-ORDER -> conservative lgkmcnt(0) waits serialize
// the pipe. Fix: DS-only in-loop traffic. Weights staged once into LDS
// (compile-time-indexed kernarg reads by lane 0), then a rolling 32-slot
// VGPR window: preload w[0..31] from kernarg; per step j refill
// wreg[(j+17)&31] = wlds[j+17] (16 steps ahead of first use). All wreg/acc
// indices compile-time -> registers. Per step: 2 ds_read + 16 FMA.
//  - Interior (x or y in [90,934)): composed 181-tap conv, weights =
//    w10*w20*w40 composed on host in double.
//  - Edge bands (90 px each side): exact 3-stage 61-tap chain in LDS
//    (unchanged from r12, measured correct).

#define HH 1024
#define WW 1024
#define BB 8
#define CC 3

struct GW181 { float w[181]; };                 // composed interior weights
struct GW3   { float a[61]; float b[61]; float c[61]; };  // w10,w20,w40

// ---------------------------------------------------------------------------
// Fused horizontal interior: out cols [90,934). Block = 32 rows x 128 cols.
// LDS tile 32 x 309 (stride odd -> conflict-free) + wlds[184].
// 40288 B -> 4 blocks/CU. 256 thr = 32 y x 8 xg, 16 outputs/thread,
// 196-step sliding window, rolling 32-slot weight window in VGPRs.
// ---------------------------------------------------------------------------
__global__ __launch_bounds__(256) void hfused(const float* __restrict__ in,
                                              float* __restrict__ out, GW181 g) {
    __shared__ float tile[32][309];
    __shared__ __align__(16) float wlds[184];
    const int x0 = 90 + 128 * blockIdx.x;       // 0..6
    const int y0 = blockIdx.y * 32;             // 0..31
    const int bc = blockIdx.z;                  // 0..23
    const int t  = threadIdx.x;

    const float* __restrict__ src = in + ((size_t)bc * HH + y0) * WW;
    {   // stage 32 rows x 308 cols (u = x0-90+c; clamp only right edge)
        const int lane = t & 63, rg = t >> 6;
        #pragma unroll
        for (int k = 0; k < 8; ++k) {
            const int r = rg + 4 * k;
            const float* srow = src + (size_t)r * WW;
            #pragma unroll
            for (int m = 0; m < 5; ++m) {
                const int c = lane + 64 * m;
                if (c < 308) tile[r][c] = srow[min(x0 - 90 + c, WW - 1)];
            }
        }
    }
    if (t == 0) {   // weights -> LDS, all indices compile-time (no scratch)
        #pragma unroll
        for (int q = 0; q < 45; ++q)
            *(float4*)&wlds[4 * q] = make_float4(g.w[4*q], g.w[4*q+1],
                                                 g.w[4*q+2], g.w[4*q+3]);
        wlds[180] = g.w[180];
    }
    __syncthreads();

    const int y = t & 31, xg = t >> 5;

    float wreg[32];                             // rolling weight window
    #pragma unroll
    for (int k = 0; k < 32; ++k) wreg[k] = g.w[k];   // compile-time kernarg

    float acc[16];
    #pragma unroll
    for (int i = 0; i < 16; ++i) acc[i] = 0.f;

    #pragma unroll
    for (int j = 0; j < 196; ++j) {             // tap tt = j - i
        const float v = tile[y][xg * 16 + j];
        #pragma unroll
        for (int i = 0; i < 16; ++i) {
            const int tt = j - i;
            if (tt >= 0 && tt < 181)
                acc[i] = fmaf(wreg[tt & 31], v, acc[i]);
        }
        if (j + 17 >= 32 && j + 17 <= 180)      // refill 16 steps ahead
            wreg[(j + 17) & 31] = wlds[j + 17];
    }

    float* drow = out + ((size_t)bc * HH + y0 + y) * WW + x0 + xg * 16;
    #pragma unroll
    for (int i = 0; i < 16; ++i)
        if (x0 + xg * 16 + i < 934) drow[i] = acc[i];
}

// ---------------------------------------------------------------------------
// Fused vertical interior: out rows [90,934). Block = 32 cols x 128 rows.
// LDS tile 308 x 32 (bank = col -> 2 lanes/bank, free) + wlds[184].
// 40160 B -> 4 blocks/CU. Same rolling-window compute as hfused.
// ---------------------------------------------------------------------------
__global__ __launch_bounds__(256) void vfused(const float* __restrict__ in,
                                              float* __restrict__ out, GW181 g) {
    __shared__ float tile[308][32];
    __shared__ __align__(16) float wlds[184];
    const int Y0 = 90 + 128 * blockIdx.x;       // 0..6
    const int x0 = blockIdx.y * 32;             // 0..31
    const int bc = blockIdx.z;
    const int t  = threadIdx.x;

    const float* __restrict__ src = in + (size_t)bc * (HH * (size_t)WW);
    {   // stage 308 rows x 32 cols
        const int col = t & 31, rg = t >> 5;
        #pragma unroll
        for (int k = 0; k < 39; ++k) {
            const int r = rg + 8 * k;
            if (r < 308) {
                const int u = min(Y0 - 90 + r, HH - 1);
                tile[r][col] = src[(size_t)u * WW + x0 + col];
            }
        }
    }
    if (t == 0) {
        #pragma unroll
        for (int q = 0; q < 45; ++q)
            *(float4*)&wlds[4 * q] = make_float4(g.w[4*q], g.w[4*q+1],
                                                 g.w[4*q+2], g.w[4*q+3]);
        wlds[180] = g.w[180];
    }
    __syncthreads();

    const int col = t & 31, yo = (t >> 5) * 16;

    float wreg[32];
    #pragma unroll
    for (int k = 0; k < 32; ++k) wreg[k] = g.w[k];

    float acc[16];
    #pragma unroll
    for (int i = 0; i < 16; ++i) acc[i] = 0.f;

    #pragma unroll
    for (int j = 0; j < 196; ++j) {
        const float v = tile[yo + j][col];
        #pragma unroll
        for (int i = 0; i < 16; ++i) {
            const int tt = j - i;
            if (tt >= 0 && tt < 181)
                acc[i] = fmaf(wreg[tt & 31], v, acc[i]);
        }
        if (j + 17 >= 32 && j + 17 <= 180)
            wreg[(j + 17) & 31] = wlds[j + 17];
    }

    float* dst = out + (size_t)bc * (HH * (size_t)WW) + x0 + col;
    #pragma unroll
    for (int i = 0; i < 16; ++i) {
        const int yy = Y0 + yo + i;
        if (yy < 934) dst[(size_t)yy * WW] = acc[i];
    }
}

// ---------------------------------------------------------------------------
// Horizontal edge bands (x<90 and x>=934 via mirror): exact 3-stage chain
// computed in LDS. Unchanged from r12 (measured correct).
// ---------------------------------------------------------------------------
__global__ __launch_bounds__(256) void hedge(const float* __restrict__ in,
                                             float* __restrict__ out, GW3 g) {
    __shared__ float s0[16][217], s1[16][185], s2[16][153];
    const int ys   = blockIdx.x;                // 64 strips of 16 rows
    const int bc   = blockIdx.y;
    const int side = blockIdx.z;
    const int t    = threadIdx.x;

    const float* __restrict__ src = in + ((size_t)bc * HH + ys * 16) * WW;
    {   // stage: s0[r][c] = in(row, mirror(max(c-32,0)))
        const int lane = t & 63, rg = t >> 6;
        #pragma unroll
        for (int k = 0; k < 4; ++k) {
            const int r = rg + 4 * k;
            #pragma unroll
            for (int m = 0; m < 4; ++m) {
                const int c = lane + 64 * m;
                if (c < 217) {
                    int u = max(c - 32, 0);
                    if (side) u = WW - 1 - u;
                    s0[r][c] = src[(size_t)r * WW + u];
                }
            }
        }
    }
    __syncthreads();

    const int y = t >> 4, xl = t & 15;

    if (xl < 15) {  // A1(z) = sum_r w10[r] * in(z+r-30), z in [10*xl, +10)
        float a[10];
        #pragma unroll
        for (int i = 0; i < 10; ++i) a[i] = 0.f;
        const int z0 = 10 * xl;
        #pragma unroll
        for (int j = 0; j < 70; ++j) {
            const float v = s0[y][z0 + 2 + j];
            #pragma unroll
            for (int i = 0; i < 10; ++i) {
                const int r = j - i;
                if (r >= 0 && r < 61) a[i] = fmaf(g.a[r], v, a[i]);
            }
        }
        #pragma unroll
        for (int i = 0; i < 10; ++i) s1[y][z0 + 32 + i] = a[i];
        if (xl == 0)
            for (int p = 0; p < 32; ++p) s1[y][p] = a[0];   // replicate pad
    }
    __syncthreads();

    if (xl < 15) {  // A2(z) = sum_s w20[s] * A1(z+s-30), z in [8*xl, +8)
        float a[8];
        #pragma unroll
        for (int i = 0; i < 8; ++i) a[i] = 0.f;
        const int z0 = 8 * xl;
        #pragma unroll
        for (int j = 0; j < 68; ++j) {
            const float v = s1[y][z0 + 2 + j];
            #pragma unroll
            for (int i = 0; i < 8; ++i) {
                const int r = j - i;
                if (r >= 0 && r < 61) a[i] = fmaf(g.b[r], v, a[i]);
            }
        }
        #pragma unroll
        for (int i = 0; i < 8; ++i) s2[y][z0 + 32 + i] = a[i];
        if (xl == 0)
            for (int p = 0; p < 32; ++p) s2[y][p] = a[0];
    }
    __syncthreads();

    if (xl < 15) {  // out(x) = sum_t w40[t] * A2(x+t-30), x in [6*xl, +6)
        float a[6];
        #pragma unroll
        for (int i = 0; i < 6; ++i) a[i] = 0.f;
        const int z0 = 6 * xl;
        #pragma unroll
        for (int j = 0; j < 66; ++j) {
            const float v = s2[y][z0 + 2 + j];
            #pragma unroll
            for (int i = 0; i < 6; ++i) {
                const int r = j - i;
                if (r >= 0 && r < 61) a[i] = fmaf(g.c[r], v, a[i]);
            }
        }
        float* drow = out + ((size_t)bc * HH + ys * 16 + y) * WW;
        #pragma unroll
        for (int i = 0; i < 6; ++i) {
            const int gx = z0 + i;
            drow[side ? (WW - 1 - gx) : gx] = a[i];
        }
    }
}

// ---------------------------------------------------------------------------
// Vertical edge bands (y<90 and y>=934 via mirror): transposed hedge.
// Unchanged from r12 (measured correct).
// ---------------------------------------------------------------------------
__global__ __launch_bounds__(256) void vedge(const float* __restrict__ in,
                                             float* __restrict__ out, GW3 g) {
    __shared__ float s0[217][17], s1[185][17], s2[153][17];
    const int xs   = blockIdx.x;                // 64 strips of 16 cols
    const int bc   = blockIdx.y;
    const int side = blockIdx.z;
    const int t    = threadIdx.x;
    const int cx   = t & 15, zl = t >> 4;

    const float* __restrict__ src = in + (size_t)bc * (HH * (size_t)WW);
    {   // stage: s0[r][cx] = in(mirror(max(r-32,0)), xs*16+cx)
        #pragma unroll
        for (int k = 0; k < 14; ++k) {
            const int r = zl + 16 * k;
            if (r < 217) {
                int u = max(r - 32, 0);
                if (side) u = HH - 1 - u;
                s0[r][cx] = src[(size_t)u * WW + xs * 16 + cx];
            }
        }
    }
    __syncthreads();

    if (zl < 15) {  // A1 rows [10*zl, +10)
        float a[10];
        #pragma unroll
        for (int i = 0; i < 10; ++i) a[i] = 0.f;
        const int z0 = 10 * zl;
        #pragma unroll
        for (int j = 0; j < 70; ++j) {
            const float v = s0[z0 + 2 + j][cx];
            #pragma unroll
            for (int i = 0; i < 10; ++i) {
                const int r = j - i;
                if (r >= 0 && r < 61) a[i] = fmaf(g.a[r], v, a[i]);
            }
        }
        #pragma unroll
        for (int i = 0; i < 10; ++i) s1[z0 + 32 + i][cx] = a[i];
        if (zl == 0)
            for (int p = 0; p < 32; ++p) s1[p][cx] = a[0];
    }
    __syncthreads();

    if (zl < 15) {  // A2 rows [8*zl, +8)
        float a[8];
        #pragma unroll
        for (int i = 0; i < 8; ++i) a[i] = 0.f;
        const int z0 = 8 * zl;
        #pragma unroll
        for (int j = 0; j < 68; ++j) {
            const float v = s1[z0 + 2 + j][cx];
            #pragma unroll
            for (int i = 0; i < 8; ++i) {
                const int r = j - i;
                if (r >= 0 && r < 61) a[i] = fmaf(g.b[r], v, a[i]);
            }
        }
        #pragma unroll
        for (int i = 0; i < 8; ++i) s2[z0 + 32 + i][cx] = a[i];
        if (zl == 0)
            for (int p = 0; p < 32; ++p) s2[p][cx] = a[0];
    }
    __syncthreads();

    if (zl < 15) {  // out rows [6*zl, +6)
        float a[6];
        #pragma unroll
        for (int i = 0; i < 6; ++i) a[i] = 0.f;
        const int z0 = 6 * zl;
        #pragma unroll
        for (int j = 0; j < 66; ++j) {
            const float v = s2[z0 + 2 + j][cx];
            #pragma unroll
            for (int i = 0; i < 6; ++i) {
                const int r = j - i;
                if (r >= 0 && r < 61) a[i] = fmaf(g.c[r], v, a[i]);
            }
        }
        #pragma unroll
        for (int i = 0; i < 6; ++i) {
            const int gy = z0 + i;
            const int Y  = side ? (HH - 1 - gy) : gy;
            out[(size_t)bc * (HH * (size_t)WW) + (size_t)Y * WW + xs * 16 + cx] = a[i];
        }
    }
}

// ---------------------------------------------------------------------------
static void gauss61(double sigma, double* w) {
    double s = 0.0;
    for (int k = 0; k < 61; ++k) {
        const double d = (double)(k - 30);
        w[k] = exp(-(d * d) / (2.0 * sigma * sigma));
        s += w[k];
    }
    for (int k = 0; k < 61; ++k) w[k] /= s;
}

extern "C" void kernel_launch(void* const* d_in, const int* in_sizes, int n_in,
                              void* d_out, int out_size, void* d_ws, size_t ws_size,
                              hipStream_t stream) {
    const float* input = (const float*)d_in[0];
    float* out = (float*)d_out;
    float* tmp = (float*)d_ws;                  // 96 MiB scratch (H result)

    double w10[61], w20[61], w40[61], c1[121], W[181];
    gauss61(10.0, w10); gauss61(20.0, w20); gauss61(40.0, w40);
    for (int k = 0; k < 121; ++k) c1[k] = 0.0;
    for (int i = 0; i < 61; ++i)
        for (int j = 0; j < 61; ++j) c1[i + j] += w10[i] * w20[j];
    for (int k = 0; k < 181; ++k) W[k] = 0.0;
    for (int i = 0; i < 121; ++i)
        for (int j = 0; j < 61; ++j) W[i + j] += c1[i] * w40[j];

    GW181 gi;
    for (int k = 0; k < 181; ++k) gi.w[k] = (float)W[k];
    GW3 ge;
    for (int k = 0; k < 61; ++k) {
        ge.a[k] = (float)w10[k];
        ge.b[k] = (float)w20[k];
        ge.c[k] = (float)w40[k];
    }

    const dim3 tb(256);
    const dim3 gh(7, 32, BB * CC);              // interior H: 5376 blocks
    const dim3 gv(7, 32, BB * CC);              // interior V
    const dim3 ge_h(64, BB * CC, 2);            // H edge bands
    const dim3 ge_v(64, BB * CC, 2);            // V edge bands

    hfused<<<gh, tb, 0, stream>>>(input, tmp, gi);
    hedge <<<ge_h, tb, 0, stream>>>(input, tmp, ge);
    vfused<<<gv, tb, 0, stream>>>(tmp, out, gi);
    vedge <<<ge_v, tb, 0, stream>>>(tmp, out, ge);
}

// Round 14
// 792.778 us; speedup vs baseline: 23.0914x; 23.0914x over previous
//
#include <hip/hip_runtime.h>
#include <math.h>

// DomainTransformFilter on [8,3,1024,1024] f32.
// Reference: 3 iterations of {61-tap H Gaussian, 61-tap V Gaussian},
// replicate pad, sigma=10/20/40. Edge-weight multiplies s=w/(w+1e-8) are
// within 7.4e-8 of 1 and dropped (validated: absmax 3.9e-3, thr ~1.1e-2).
//
// Round-14. Fusion structure (r12: passed, FETCH ideal, 0 conflicts) with
// COMPILE-TIME WEIGHTS. History:
//  - r12: weights as kernel args -> in-loop s_load refetches; SMEM+DS share
//    lgkmcnt out-of-order -> conservative waits; VALUBusy 37.8%, 326 us.
//  - r13: rolling VGPR weight window broke full unroll -> runtime-indexed
//    regs -> scratch (VGPR=256, 9 GB scratch traffic, 9.1 ms). Rule #20.
//  - r14: sigma is a compile-time constant, so ALL weights are constexpr:
//    exp(-d^2/2s^2) = q^(d^2), q = exp(-1/2s^2) as a double literal,
//    q^(d^2) by constexpr integer power (~1e-13 rel err, << fp32 eps).
//    Every tap folds to an inline literal in its FMA: no s_loads, no LDS
//    weight reads, no SGPR pressure. Loop body is simpler than r12's
//    (which fully unrolled at 52 VGPR).
//  - Interior (x or y in [90,934)): composed 181-tap conv (w10*w20*w40).
//  - Edge bands (90 px each side): exact 3-stage 61-tap chain in LDS
//    (iterated-clamp != direct-clamp), right/bottom via mirror symmetry.

#define HH 1024
#define WW 1024
#define BB 8
#define CC 3

// ---------------------------------------------------------------------------
// Compile-time weight tables.
// ---------------------------------------------------------------------------
constexpr double qpow(double q, int e) {
    double r = 1.0;
    for (int i = 0; i < e; ++i) r *= q;
    return r;
}

struct WTab {
    float w181[181];                 // composed interior weights
    float a[61], b[61], c[61];       // w10, w20, w40
};

constexpr WTab make_wt() {
    WTab t{};
    // exp(-1/(2*sigma^2)) as double literals (Taylor to 1e-17):
    const double q10 = 0.9950124791926823;   // sigma = 10
    const double q20 = 0.9987507809245809;   // sigma = 20
    const double q40 = 0.9996875488230391;   // sigma = 40
    double w10[61] = {}, w20[61] = {}, w40[61] = {};
    double s10 = 0.0, s20 = 0.0, s40 = 0.0;
    for (int k = 0; k < 61; ++k) {
        const int d = k - 30, e = d * d;
        w10[k] = qpow(q10, e); s10 += w10[k];
        w20[k] = qpow(q20, e); s20 += w20[k];
        w40[k] = qpow(q40, e); s40 += w40[k];
    }
    for (int k = 0; k < 61; ++k) { w10[k] /= s10; w20[k] /= s20; w40[k] /= s40; }
    double c1[121] = {};
    for (int i = 0; i < 61; ++i)
        for (int j = 0; j < 61; ++j) c1[i + j] += w10[i] * w20[j];
    double W[181] = {};
    for (int i = 0; i < 121; ++i)
        for (int j = 0; j < 61; ++j) W[i + j] += c1[i] * w40[j];
    for (int k = 0; k < 181; ++k) t.w181[k] = (float)W[k];
    for (int k = 0; k < 61; ++k) {
        t.a[k] = (float)w10[k];
        t.b[k] = (float)w20[k];
        t.c[k] = (float)w40[k];
    }
    return t;
}

constexpr WTab G = make_wt();        // all indexing below is compile-time

// ---------------------------------------------------------------------------
// Fused horizontal interior: out cols [90,934). Block = 32 rows x 128 cols.
// LDS tile 32 x 309 (stride odd -> conflict-free). 39.6 KB -> 4 blocks/CU.
// 256 thr = 32 y x 8 xg, 16 outputs/thread, 196-step sliding window.
// ---------------------------------------------------------------------------
__global__ __launch_bounds__(256) void hfused(const float* __restrict__ in,
                                              float* __restrict__ out) {
    __shared__ float tile[32][309];
    const int x0 = 90 + 128 * blockIdx.x;       // 0..6
    const int y0 = blockIdx.y * 32;             // 0..31
    const int bc = blockIdx.z;                  // 0..23
    const int t  = threadIdx.x;

    const float* __restrict__ src = in + ((size_t)bc * HH + y0) * WW;
    {   // stage 32 rows x 308 cols (u = x0-90+c; clamp only right edge)
        const int lane = t & 63, rg = t >> 6;
        #pragma unroll
        for (int k = 0; k < 8; ++k) {
            const int r = rg + 4 * k;
            const float* srow = src + (size_t)r * WW;
            #pragma unroll
            for (int m = 0; m < 5; ++m) {
                const int c = lane + 64 * m;
                if (c < 308) tile[r][c] = srow[min(x0 - 90 + c, WW - 1)];
            }
        }
    }
    __syncthreads();

    const int y = t & 31, xg = t >> 5;
    float acc[16];
    #pragma unroll
    for (int i = 0; i < 16; ++i) acc[i] = 0.f;

    #pragma unroll
    for (int j = 0; j < 196; ++j) {             // tap tt = j - i (compile-time)
        const float v = tile[y][xg * 16 + j];
        #pragma unroll
        for (int i = 0; i < 16; ++i) {
            const int tt = j - i;
            if (tt >= 0 && tt < 181)
                acc[i] = fmaf(G.w181[tt], v, acc[i]);   // inline literal
        }
    }

    float* drow = out + ((size_t)bc * HH + y0 + y) * WW + x0 + xg * 16;
    #pragma unroll
    for (int i = 0; i < 16; ++i)
        if (x0 + xg * 16 + i < 934) drow[i] = acc[i];
}

// ---------------------------------------------------------------------------
// Fused vertical interior: out rows [90,934). Block = 32 cols x 128 rows.
// LDS tile 308 x 32 (bank = col -> 2 lanes/bank, free). 38.5 KB.
// ---------------------------------------------------------------------------
__global__ __launch_bounds__(256) void vfused(const float* __restrict__ in,
                                              float* __restrict__ out) {
    __shared__ float tile[308][32];
    const int Y0 = 90 + 128 * blockIdx.x;       // 0..6
    const int x0 = blockIdx.y * 32;             // 0..31
    const int bc = blockIdx.z;
    const int t  = threadIdx.x;

    const float* __restrict__ src = in + (size_t)bc * (HH * (size_t)WW);
    {   // stage 308 rows x 32 cols
        const int col = t & 31, rg = t >> 5;
        #pragma unroll
        for (int k = 0; k < 39; ++k) {
            const int r = rg + 8 * k;
            if (r < 308) {
                const int u = min(Y0 - 90 + r, HH - 1);
                tile[r][col] = src[(size_t)u * WW + x0 + col];
            }
        }
    }
    __syncthreads();

    const int col = t & 31, yo = (t >> 5) * 16;
    float acc[16];
    #pragma unroll
    for (int i = 0; i < 16; ++i) acc[i] = 0.f;

    #pragma unroll
    for (int j = 0; j < 196; ++j) {
        const float v = tile[yo + j][col];
        #pragma unroll
        for (int i = 0; i < 16; ++i) {
            const int tt = j - i;
            if (tt >= 0 && tt < 181)
                acc[i] = fmaf(G.w181[tt], v, acc[i]);
        }
    }

    float* dst = out + (size_t)bc * (HH * (size_t)WW) + x0 + col;
    #pragma unroll
    for (int i = 0; i < 16; ++i) {
        const int yy = Y0 + yo + i;
        if (yy < 934) dst[(size_t)yy * WW] = acc[i];
    }
}

// ---------------------------------------------------------------------------
// Horizontal edge bands (x<90 and x>=934 via mirror): exact 3-stage chain
// computed in LDS. Structure unchanged from r12 (measured correct);
// weights now compile-time.
// ---------------------------------------------------------------------------
__global__ __launch_bounds__(256) void hedge(const float* __restrict__ in,
                                             float* __restrict__ out) {
    __shared__ float s0[16][217], s1[16][185], s2[16][153];
    const int ys   = blockIdx.x;                // 64 strips of 16 rows
    const int bc   = blockIdx.y;
    const int side = blockIdx.z;
    const int t    = threadIdx.x;

    const float* __restrict__ src = in + ((size_t)bc * HH + ys * 16) * WW;
    {   // stage: s0[r][c] = in(row, mirror(max(c-32,0)))
        const int lane = t & 63, rg = t >> 6;
        #pragma unroll
        for (int k = 0; k < 4; ++k) {
            const int r = rg + 4 * k;
            #pragma unroll
            for (int m = 0; m < 4; ++m) {
                const int c = lane + 64 * m;
                if (c < 217) {
                    int u = max(c - 32, 0);
                    if (side) u = WW - 1 - u;
                    s0[r][c] = src[(size_t)r * WW + u];
                }
            }
        }
    }
    __syncthreads();

    const int y = t >> 4, xl = t & 15;

    if (xl < 15) {  // A1(z) = sum_r w10[r] * in(z+r-30), z in [10*xl, +10)
        float a[10];
        #pragma unroll
        for (int i = 0; i < 10; ++i) a[i] = 0.f;
        const int z0 = 10 * xl;
        #pragma unroll
        for (int j = 0; j < 70; ++j) {
            const float v = s0[y][z0 + 2 + j];
            #pragma unroll
            for (int i = 0; i < 10; ++i) {
                const int r = j - i;
                if (r >= 0 && r < 61) a[i] = fmaf(G.a[r], v, a[i]);
            }
        }
        #pragma unroll
        for (int i = 0; i < 10; ++i) s1[y][z0 + 32 + i] = a[i];
        if (xl == 0)
            for (int p = 0; p < 32; ++p) s1[y][p] = a[0];   // replicate pad
    }
    __syncthreads();

    if (xl < 15) {  // A2(z) = sum_s w20[s] * A1(z+s-30), z in [8*xl, +8)
        float a[8];
        #pragma unroll
        for (int i = 0; i < 8; ++i) a[i] = 0.f;
        const int z0 = 8 * xl;
        #pragma unroll
        for (int j = 0; j < 68; ++j) {
            const float v = s1[y][z0 + 2 + j];
            #pragma unroll
            for (int i = 0; i < 8; ++i) {
                const int r = j - i;
                if (r >= 0 && r < 61) a[i] = fmaf(G.b[r], v, a[i]);
            }
        }
        #pragma unroll
        for (int i = 0; i < 8; ++i) s2[y][z0 + 32 + i] = a[i];
        if (xl == 0)
            for (int p = 0; p < 32; ++p) s2[y][p] = a[0];
    }
    __syncthreads();

    if (xl < 15) {  // out(x) = sum_t w40[t] * A2(x+t-30), x in [6*xl, +6)
        float a[6];
        #pragma unroll
        for (int i = 0; i < 6; ++i) a[i] = 0.f;
        const int z0 = 6 * xl;
        #pragma unroll
        for (int j = 0; j < 66; ++j) {
            const float v = s2[y][z0 + 2 + j];
            #pragma unroll
            for (int i = 0; i < 6; ++i) {
                const int r = j - i;
                if (r >= 0 && r < 61) a[i] = fmaf(G.c[r], v, a[i]);
            }
        }
        float* drow = out + ((size_t)bc * HH + ys * 16 + y) * WW;
        #pragma unroll
        for (int i = 0; i < 6; ++i) {
            const int gx = z0 + i;
            drow[side ? (WW - 1 - gx) : gx] = a[i];
        }
    }
}

// ---------------------------------------------------------------------------
// Vertical edge bands (y<90 and y>=934 via mirror): transposed hedge.
// Block = 16 cols x one side. LDS [rows][17] (stride 17, odd).
// ---------------------------------------------------------------------------
__global__ __launch_bounds__(256) void vedge(const float* __restrict__ in,
                                             float* __restrict__ out) {
    __shared__ float s0[217][17], s1[185][17], s2[153][17];
    const int xs   = blockIdx.x;                // 64 strips of 16 cols
    const int bc   = blockIdx.y;
    const int side = blockIdx.z;
    const int t    = threadIdx.x;
    const int cx   = t & 15, zl = t >> 4;

    const float* __restrict__ src = in + (size_t)bc * (HH * (size_t)WW);
    {   // stage: s0[r][cx] = in(mirror(max(r-32,0)), xs*16+cx)
        #pragma unroll
        for (int k = 0; k < 14; ++k) {
            const int r = zl + 16 * k;
            if (r < 217) {
                int u = max(r - 32, 0);
                if (side) u = HH - 1 - u;
                s0[r][cx] = src[(size_t)u * WW + xs * 16 + cx];
            }
        }
    }
    __syncthreads();

    if (zl < 15) {  // A1 rows [10*zl, +10)
        float a[10];
        #pragma unroll
        for (int i = 0; i < 10; ++i) a[i] = 0.f;
        const int z0 = 10 * zl;
        #pragma unroll
        for (int j = 0; j < 70; ++j) {
            const float v = s0[z0 + 2 + j][cx];
            #pragma unroll
            for (int i = 0; i < 10; ++i) {
                const int r = j - i;
                if (r >= 0 && r < 61) a[i] = fmaf(G.a[r], v, a[i]);
            }
        }
        #pragma unroll
        for (int i = 0; i < 10; ++i) s1[z0 + 32 + i][cx] = a[i];
        if (zl == 0)
            for (int p = 0; p < 32; ++p) s1[p][cx] = a[0];
    }
    __syncthreads();

    if (zl < 15) {  // A2 rows [8*zl, +8)
        float a[8];
        #pragma unroll
        for (int i = 0; i < 8; ++i) a[i] = 0.f;
        const int z0 = 8 * zl;
        #pragma unroll
        for (int j = 0; j < 68; ++j) {
            const float v = s1[z0 + 2 + j][cx];
            #pragma unroll
            for (int i = 0; i < 8; ++i) {
                const int r = j - i;
                if (r >= 0 && r < 61) a[i] = fmaf(G.b[r], v, a[i]);
            }
        }
        #pragma unroll
        for (int i = 0; i < 8; ++i) s2[z0 + 32 + i][cx] = a[i];
        if (zl == 0)
            for (int p = 0; p < 32; ++p) s2[p][cx] = a[0];
    }
    __syncthreads();

    if (zl < 15) {  // out rows [6*zl, +6)
        float a[6];
        #pragma unroll
        for (int i = 0; i < 6; ++i) a[i] = 0.f;
        const int z0 = 6 * zl;
        #pragma unroll
        for (int j = 0; j < 66; ++j) {
            const float v = s2[z0 + 2 + j][cx];
            #pragma unroll
            for (int i = 0; i < 6; ++i) {
                const int r = j - i;
                if (r >= 0 && r < 61) a[i] = fmaf(G.c[r], v, a[i]);
            }
        }
        #pragma unroll
        for (int i = 0; i < 6; ++i) {
            const int gy = z0 + i;
            const int Y  = side ? (HH - 1 - gy) : gy;
            out[(size_t)bc * (HH * (size_t)WW) + (size_t)Y * WW + xs * 16 + cx] = a[i];
        }
    }
}

// ---------------------------------------------------------------------------
extern "C" void kernel_launch(void* const* d_in, const int* in_sizes, int n_in,
                              void* d_out, int out_size, void* d_ws, size_t ws_size,
                              hipStream_t stream) {
    const float* input = (const float*)d_in[0];
    float* out = (float*)d_out;
    float* tmp = (float*)d_ws;                  // 96 MiB scratch (H result)

    const dim3 tb(256);
    const dim3 gh(7, 32, BB * CC);              // interior H: 5376 blocks
    const dim3 gv(7, 32, BB * CC);              // interior V
    const dim3 ge_h(64, BB * CC, 2);            // H edge bands
    const dim3 ge_v(64, BB * CC, 2);            // V edge bands

    hfused<<<gh, tb, 0, stream>>>(input, tmp);
    hedge <<<ge_h, tb, 0, stream>>>(input, tmp);
    vfused<<<gv, tb, 0, stream>>>(tmp, out);
    vedge <<<ge_v, tb, 0, stream>>>(tmp, out);
}